// Round 4
// baseline (2354.741 us; speedup 1.0000x reference)
//
#include <hip/hip_runtime.h>
#include <math.h>
#include <float.h>

namespace {

constexpr int Bb = 8, Kk = 4, BKn = 32, Dd = 1024, Ff = 4096, Vv = 32000, Tt = 16;
constexpr int GDS = 16, GDC = 64;        // gates d-split / d-chunk  (16*64 = 1024)
constexpr int LDSP = 4, LDC = 256;       // logits d-split / d-chunk (4*256 = 1024)
constexpr int NVCH = 250;                // logits vocab chunks of 128
constexpr int EOSt = 2, PADt = 0;
constexpr float BIGf = 1e9f, EOSSf = 1000.0f;

// ---- workspace layout (float indices) ----
constexpr size_t OFF_HTN = 0;                                   // hTn [1024][32]
constexpr size_t OFF_CB0 = OFF_HTN + (size_t)Dd * BKn;          // c ping [32][1024]
constexpr size_t OFF_CB1 = OFF_CB0 + (size_t)BKn * Dd;          // c pong
constexpr size_t OFF_GP  = OFF_CB1 + (size_t)BKn * Dd;          // gate partials [16][32][4096]
constexpr size_t OFF_PL  = OFF_GP  + (size_t)GDS * BKn * Ff;    // logit partials [4][4][32000][8]
constexpr size_t OFF_CS  = OFF_PL  + (size_t)LDSP * 4 * Vv * 8; // chunk stats [250][32][12]
constexpr size_t OFF_SC  = OFF_CS  + (size_t)NVCH * BKn * 12;   // scores [32]
constexpr size_t OFF_INT = OFF_SC  + BKn;                       // int region
constexpr int IW = 0, ISTOP = 32, IPREV = 40, IBUFA = 72, IBUFB = IBUFA + Bb * Kk * Tt;

__device__ inline void ins4(float v, int id, float tv[4], int ti[4]) {
#pragma unroll
  for (int r = 0; r < 4; r++) {
    bool better = (v > tv[r]) || (v == tv[r] && id < ti[r]);
    if (better) { float fv = tv[r]; int fi = ti[r]; tv[r] = v; ti[r] = id; v = fv; id = fi; }
  }
}

// merge per-lane sorted top-4 into group-global top-4. STARTOFF=32 -> 64-lane wave,
// STARTOFF=16 -> independent 32-lane halves.
template <int STARTOFF>
__device__ inline void merge_top4(float tv[4], int ti[4], float ov[4], int oi[4]) {
#pragma unroll
  for (int r = 0; r < 4; r++) {
    float hv = tv[0]; int hi = ti[0];
    float m = hv;
    for (int off = STARTOFF; off; off >>= 1) m = fmaxf(m, __shfl_xor(m, off));
    int c = (hv == m) ? hi : 0x7fffffff;
    for (int off = STARTOFF; off; off >>= 1) c = min(c, __shfl_xor(c, off));
    if (hv == m && hi == c) {   // this lane's head won: pop
      tv[0] = tv[1]; ti[0] = ti[1];
      tv[1] = tv[2]; ti[1] = ti[2];
      tv[2] = tv[3]; ti[2] = ti[3];
      tv[3] = -FLT_MAX; ti[3] = 0x7fffffff;
    }
    ov[r] = m; oi[r] = c;
  }
}

__global__ __launch_bounds__(256) void initK(const int* __restrict__ words,
    const float* __restrict__ h0, const float* __restrict__ c0,
    float* __restrict__ ws) {
  int* wsi = (int*)(ws + OFF_INT);
  if (blockIdx.x < 128) {
    int g = blockIdx.x * 256 + threadIdx.x;   // 0..32767
    int d = g >> 5, bk = g & 31;
    ws[OFF_HTN + g] = h0[(size_t)bk * Dd + d];   // transpose to [d][bk]
    ws[OFF_CB0 + g] = c0[g];                     // [32][1024] linear
  } else {
    int t = threadIdx.x;
    if (t < BKn) {
      ws[OFF_SC + t] = ((t & 3) == 0) ? 0.f : BIGf;
      wsi[IW + t] = words[t];
      wsi[IPREV + t] = t & 3;                    // identity gather for step 0
    }
    if (t < Bb) wsi[ISTOP + t] = 0;
    for (int i = t; i < 2 * Bb * Kk * Tt; i += 256) wsi[IBUFA + i] = 0;
  }
}

// gates partial GEMM. Gathers x=E[w] and h=hTn[.][src] into LDS directly.
// grid (16, 16): x = 256-col tile of f, y = d-chunk of 64.
__global__ __launch_bounds__(256) void gatesK(const float* __restrict__ Wx,
    const float* __restrict__ Wh, const float* __restrict__ E,
    const float* __restrict__ hTn, const int* __restrict__ wsi,
    float* __restrict__ Gp) {
  __shared__ float xs[GDC][BKn], hs[GDC][BKn];
  int tid = threadIdx.x;
  int d0 = blockIdx.y * GDC;
  {
    int bk = tid & 31, dq = tid >> 5;           // dq 0..7, 8 d each
    int w = wsi[IW + bk];
    int src = (bk & ~3) | wsi[IPREV + bk];
    const float* Erow = E + (size_t)w * Dd + d0;
#pragma unroll
    for (int k = 0; k < 8; k++) {
      int d = dq * 8 + k;
      xs[d][bk] = Erow[d];
      hs[d][bk] = hTn[(size_t)(d0 + d) * BKn + src];
    }
  }
  __syncthreads();
  int ct = tid & 63, bg = tid >> 6;
  int f0 = blockIdx.x * 256 + ct * 4;
  float acc[4][8];
#pragma unroll
  for (int c = 0; c < 4; c++)
#pragma unroll
    for (int i = 0; i < 8; i++) acc[c][i] = 0.f;
#pragma unroll 4
  for (int d = 0; d < GDC; ++d) {
    float4 wx = *(const float4*)(Wx + (size_t)(d0 + d) * Ff + f0);
    float4 wh = *(const float4*)(Wh + (size_t)(d0 + d) * Ff + f0);
    float4 xlo = *(const float4*)&xs[d][bg * 8];
    float4 xhi = *(const float4*)&xs[d][bg * 8 + 4];
    float4 hlo = *(const float4*)&hs[d][bg * 8];
    float4 hhi = *(const float4*)&hs[d][bg * 8 + 4];
    float xv[8] = {xlo.x, xlo.y, xlo.z, xlo.w, xhi.x, xhi.y, xhi.z, xhi.w};
    float hv[8] = {hlo.x, hlo.y, hlo.z, hlo.w, hhi.x, hhi.y, hhi.z, hhi.w};
    float wxc[4] = {wx.x, wx.y, wx.z, wx.w};
    float whc[4] = {wh.x, wh.y, wh.z, wh.w};
#pragma unroll
    for (int c = 0; c < 4; c++)
#pragma unroll
      for (int i = 0; i < 8; i++)
        acc[c][i] = fmaf(xv[i], wxc[c], fmaf(hv[i], whc[c], acc[c][i]));
  }
#pragma unroll
  for (int i = 0; i < 8; i++) {
    int bk = bg * 8 + i;
    float4 o = {acc[0][i], acc[1][i], acc[2][i], acc[3][i]};
    *(float4*)(Gp + ((size_t)blockIdx.y * BKn + bk) * Ff + f0) = o;
  }
}

// reduce 16 gate partials + bias -> nonlinearity; gathers c by prev; writes c_new, hTn.
// grid (32): block = beam, 256 threads, 1 float4 of dc each.
__global__ __launch_bounds__(256) void lstmK(const float* __restrict__ bvec,
    const float* __restrict__ Gp, const float* __restrict__ cPrev,
    const int* __restrict__ wsi, float* __restrict__ cNew,
    float* __restrict__ hTn) {
  int bk = blockIdx.x;
  int dc = threadIdx.x * 4;
  float4 g4[4];
#pragma unroll
  for (int g = 0; g < 4; g++) g4[g] = *(const float4*)(bvec + g * Dd + dc);
#pragma unroll 8
  for (int ds = 0; ds < GDS; ds++) {
#pragma unroll
    for (int g = 0; g < 4; g++) {
      float4 p = *(const float4*)(Gp + ((size_t)ds * BKn + bk) * Ff + g * Dd + dc);
      g4[g].x += p.x; g4[g].y += p.y; g4[g].z += p.z; g4[g].w += p.w;
    }
  }
  int src = (bk & ~3) | wsi[IPREV + bk];
  float4 c4 = *(const float4*)(cPrev + (size_t)src * Dd + dc);
  float ci[4] = {g4[0].x, g4[0].y, g4[0].z, g4[0].w};
  float cf[4] = {g4[1].x, g4[1].y, g4[1].z, g4[1].w};
  float cg[4] = {g4[2].x, g4[2].y, g4[2].z, g4[2].w};
  float co[4] = {g4[3].x, g4[3].y, g4[3].z, g4[3].w};
  float cv[4] = {c4.x, c4.y, c4.z, c4.w};
  float cn[4], hn[4];
#pragma unroll
  for (int j = 0; j < 4; j++) {
    float si = 1.f / (1.f + expf(-ci[j]));
    float sf = 1.f / (1.f + expf(-cf[j]));
    float so = 1.f / (1.f + expf(-co[j]));
    float tg = tanhf(cg[j]);
    cn[j] = sf * cv[j] + si * tg;
    hn[j] = so * tanhf(cn[j]);
  }
  float4 cno = {cn[0], cn[1], cn[2], cn[3]};
  *(float4*)(cNew + (size_t)bk * Dd + dc) = cno;
#pragma unroll
  for (int j = 0; j < 4; j++) hTn[(size_t)(dc + j) * BKn + bk] = hn[j];
}

// logits partial GEMM. grid (125, 4): x = 256-col tile of v, y = d-chunk of 256.
// P layout: [ds][bg][32000][8 beams], stores contiguous 32B per (thread,col).
__global__ __launch_bounds__(256) void logitsK(const float* __restrict__ Wo,
    const float* __restrict__ hTn, float* __restrict__ P) {
  __shared__ float hs[LDC][BKn];
  int tid = threadIdx.x;
  int d0 = blockIdx.y * LDC;
  {
    int bk = tid & 31, dq = tid >> 5;
#pragma unroll
    for (int k = 0; k < 32; k++) {
      int d = dq * 32 + k;
      hs[d][bk] = hTn[(size_t)(d0 + d) * BKn + bk];
    }
  }
  __syncthreads();
  int ct = tid & 63, bg = tid >> 6;
  size_t v0 = (size_t)blockIdx.x * 256 + ct * 4;
  float acc[4][8];
#pragma unroll
  for (int c = 0; c < 4; c++)
#pragma unroll
    for (int i = 0; i < 8; i++) acc[c][i] = 0.f;
#pragma unroll 8
  for (int d = 0; d < LDC; ++d) {
    float4 w = *(const float4*)(Wo + (size_t)(d0 + d) * Vv + v0);
    float4 hlo = *(const float4*)&hs[d][bg * 8];
    float4 hhi = *(const float4*)&hs[d][bg * 8 + 4];
    float hv[8] = {hlo.x, hlo.y, hlo.z, hlo.w, hhi.x, hhi.y, hhi.z, hhi.w};
    float wc[4] = {w.x, w.y, w.z, w.w};
#pragma unroll
    for (int c = 0; c < 4; c++)
#pragma unroll
      for (int i = 0; i < 8; i++)
        acc[c][i] = fmaf(hv[i], wc[c], acc[c][i]);
  }
  float* base = P + ((size_t)(blockIdx.y * 4 + bg) * Vv) * 8;
#pragma unroll
  for (int c = 0; c < 4; c++) {
    float4 lo = {acc[c][0], acc[c][1], acc[c][2], acc[c][3]};
    float4 hi = {acc[c][4], acc[c][5], acc[c][6], acc[c][7]};
    *(float4*)(base + (v0 + c) * 8) = lo;
    *(float4*)(base + (v0 + c) * 8 + 4) = hi;
  }
}

// reduce 4 logit partials + bias -> full logits in LDS -> chunk stats (max/sumexp/top4).
// grid 250 blocks x 256 threads; block = 128 vocab cols; all 4 waves do stats (8 beams each).
__global__ __launch_bounds__(256) void logitsRedK(const float* __restrict__ P,
    const float* __restrict__ bo, float* __restrict__ cs) {
  __shared__ float sd[BKn][128];
  int tid = threadIdx.x;
  int vl = tid & 127, bh = tid >> 7;     // bh: beam half (16 beams each)
  size_t v = (size_t)blockIdx.x * 128 + vl;
  float b = bo[v];
#pragma unroll
  for (int bgl = 0; bgl < 2; bgl++) {
    int bg = bh * 2 + bgl;
    float4 lo = {0, 0, 0, 0}, hi = {0, 0, 0, 0};
#pragma unroll
    for (int ds = 0; ds < LDSP; ds++) {
      const float* p = P + ((size_t)(ds * 4 + bg) * Vv + v) * 8;
      float4 a = *(const float4*)p;
      float4 c = *(const float4*)(p + 4);
      lo.x += a.x; lo.y += a.y; lo.z += a.z; lo.w += a.w;
      hi.x += c.x; hi.y += c.y; hi.z += c.z; hi.w += c.w;
    }
    int bk0 = bg * 8;
    sd[bk0 + 0][vl] = lo.x + b; sd[bk0 + 1][vl] = lo.y + b;
    sd[bk0 + 2][vl] = lo.z + b; sd[bk0 + 3][vl] = lo.w + b;
    sd[bk0 + 4][vl] = hi.x + b; sd[bk0 + 5][vl] = hi.y + b;
    sd[bk0 + 6][vl] = hi.z + b; sd[bk0 + 7][vl] = hi.w + b;
  }
  __syncthreads();
  int lane = tid & 63;
  int wv_ = tid >> 6;                     // 4 waves x 8 beams = 32 beams
  int i0 = blockIdx.x * 128 + lane;
  int i1 = i0 + 64;
  for (int bb = 0; bb < 8; ++bb) {
    int bk = wv_ * 8 + bb;
    float v0f = sd[bk][lane];
    float v1f = sd[bk][lane + 64];
    float m = fmaxf(v0f, v1f);
    for (int off = 32; off; off >>= 1) m = fmaxf(m, __shfl_xor(m, off));
    float se = expf(v0f - m) + expf(v1f - m);
    for (int off = 32; off; off >>= 1) se += __shfl_xor(se, off);
    float tv[4]; int ti[4];
#pragma unroll
    for (int r = 0; r < 4; r++) { tv[r] = -FLT_MAX; ti[r] = 0x7fffffff; }
    ins4(v0f, i0, tv, ti);
    ins4(v1f, i1, tv, ti);
    float ov[4]; int oi[4];
    merge_top4<32>(tv, ti, ov, oi);
    if (lane == 0) {
      float* p = cs + ((size_t)blockIdx.x * BKn + bk) * 12;
      p[0] = m; p[1] = se;
#pragma unroll
      for (int r = 0; r < 4; r++) { p[2 + r] = ov[r]; p[6 + r] = __int_as_float(oi[r]); }
    }
  }
}

// fused: per-beam merge of 250 chunk stats -> lse + top4; then exact selection,
// EOS logic, buf ping-pong. One block of 1024 threads. No runtime-indexed arrays.
__global__ __launch_bounds__(1024) void redSelK(float* __restrict__ ws, int step) {
  __shared__ float bt_s[BKn][8];
  __shared__ int s_tok[BKn], s_prevb[BKn];
  int* wsi = (int*)(ws + OFF_INT);
  const float* cs = ws + OFF_CS;
  int tid = threadIdx.x;
  int wv = tid >> 6, lane = tid & 63;
  {
    int half = lane >> 5, l32 = lane & 31;
    int bk = wv * 2 + half;                 // 16 waves x 2 halves = 32 beams
    float tv[4]; int ti[4];
#pragma unroll
    for (int r = 0; r < 4; r++) { tv[r] = -FLT_MAX; ti[r] = 0x7fffffff; }
    float cm[8], csum[8]; bool val[8];
    float lm = -FLT_MAX;
#pragma unroll
    for (int q = 0; q < 8; q++) {
      int c = l32 + 32 * q;
      val[q] = c < NVCH;
      if (val[q]) {
        const float* p = cs + ((size_t)c * BKn + bk) * 12;
        cm[q] = p[0]; csum[q] = p[1];
        lm = fmaxf(lm, cm[q]);
#pragma unroll
        for (int r = 0; r < 4; r++) ins4(p[2 + r], __float_as_int(p[6 + r]), tv, ti);
      } else { cm[q] = -FLT_MAX; csum[q] = 0.f; }
    }
    float M = lm;
    for (int off = 16; off; off >>= 1) M = fmaxf(M, __shfl_xor(M, off));
    float ls = 0.f;
#pragma unroll
    for (int q = 0; q < 8; q++) if (val[q]) ls += csum[q] * expf(cm[q] - M);
    for (int off = 16; off; off >>= 1) ls += __shfl_xor(ls, off);
    float lse = M + logf(ls);
    float ov[4]; int oi[4];
    merge_top4<16>(tv, ti, ov, oi);
    if (l32 == 0) {
#pragma unroll
      for (int r = 0; r < 4; r++) {
        bt_s[bk][r] = lse - ov[r];
        bt_s[bk][4 + r] = __int_as_float(oi[r]);
      }
    }
  }
  __syncthreads();
  if (tid < Bb) {
    int b = tid;
    int st = wsi[ISTOP + b];
    float sc[4];
#pragma unroll
    for (int k = 0; k < 4; k++) sc[k] = ws[OFF_SC + b * 4 + k];
    float cval[16]; int ctok[16];
#pragma unroll
    for (int kb = 0; kb < 4; kb++)
#pragma unroll
      for (int r = 0; r < 4; r++) {
        cval[kb * 4 + r] = bt_s[b * 4 + kb][r] + sc[kb];
        ctok[kb * 4 + r] = __float_as_int(bt_s[b * 4 + kb][4 + r]);
      }
    float selS[4]; int selW[4], prevK[4];
    int usedMask = 0;
#pragma unroll
    for (int r = 0; r < 4; r++) {
      int best = -1; float bv = FLT_MAX;
#pragma unroll
      for (int t = 0; t < 16; t++) {
        if (!((usedMask >> t) & 1) && cval[t] < bv) { bv = cval[t]; best = t; }
      }
      usedMask |= 1 << best;
      int tok = 0;
#pragma unroll
      for (int t = 0; t < 16; t++) if (t == best) tok = ctok[t];   // no runtime index
      selS[r] = bv; selW[r] = tok; prevK[r] = best >> 2;
    }
    bool eos[4];
#pragma unroll
    for (int r = 0; r < 4; r++) eos[r] = (selW[r] == EOSt);
    bool first = eos[0] && !st;
#pragma unroll
    for (int r = 0; r < 4; r++) if (eos[r] && !first && !st) selS[r] = EOSSf;
#pragma unroll
    for (int k = 0; k < 4; k++) {
      int tok = st ? PADt : (first ? EOSt : selW[k]);
      int pb  = st ? k : prevK[k];
      s_tok[b * 4 + k] = tok;
      s_prevb[b * 4 + k] = pb;
      if (!st) { ws[OFF_SC + b * 4 + k] = selS[k]; wsi[IW + b * 4 + k] = selW[k]; }
      wsi[IPREV + b * 4 + k] = prevK[k];
    }
    wsi[ISTOP + b] = (st || first) ? 1 : 0;
  }
  __syncthreads();
  if (tid < 512) {
    const int* br = wsi + (((step & 1) == 0) ? IBUFA : IBUFB);
    int* bw = wsi + (((step & 1) == 0) ? IBUFB : IBUFA);
    int bkk = tid >> 4, t = tid & 15;
    int pb = s_prevb[bkk];
    int src = ((bkk & ~3) | pb) * Tt + t;
    int val = br[src];
    if (t == step) val = s_tok[bkk];
    bw[tid] = val;
  }
}

// Output read as float32 by harness: tokens as float values, scores as floats.
__global__ __launch_bounds__(256) void outK(const float* __restrict__ ws,
                                            float* __restrict__ out) {
  const int* wsi = (const int*)(ws + OFF_INT);
  int g = blockIdx.x * 256 + threadIdx.x;
  if (g < Bb * Kk * Tt) {
    out[g] = (float)wsi[IBUFA + g];               // final buf in A after 16 steps
  } else if (g < Bb * Kk * Tt + BKn) {
    out[g] = ws[OFF_SC + (g - Bb * Kk * Tt)];
  }
}

} // namespace

extern "C" void kernel_launch(void* const* d_in, const int* in_sizes, int n_in,
                              void* d_out, int out_size, void* d_ws, size_t ws_size,
                              hipStream_t stream) {
  (void)in_sizes; (void)n_in; (void)out_size; (void)ws_size;
  const int*   words = (const int*)d_in[0];
  const float* h0 = (const float*)d_in[1];
  const float* c0 = (const float*)d_in[2];
  const float* E  = (const float*)d_in[3];
  const float* Wx = (const float*)d_in[4];
  const float* Wh = (const float*)d_in[5];
  const float* bv = (const float*)d_in[6];
  const float* Wo = (const float*)d_in[7];
  const float* bo = (const float*)d_in[8];
  float* ws = (float*)d_ws;
  float* hTn = ws + OFF_HTN;
  float* cb0 = ws + OFF_CB0;
  float* cb1 = ws + OFF_CB1;
  float* Gp  = ws + OFF_GP;
  float* P   = ws + OFF_PL;
  float* cs  = ws + OFF_CS;
  int*   wsi = (int*)(ws + OFF_INT);

  initK<<<129, 256, 0, stream>>>(words, h0, c0, ws);
  for (int j = 0; j < Tt; j++) {
    float* cPrev = (j & 1) ? cb1 : cb0;
    float* cNext = (j & 1) ? cb0 : cb1;
    gatesK<<<dim3(16, GDS), 256, 0, stream>>>(Wx, Wh, E, hTn, wsi, Gp);
    lstmK<<<32, 256, 0, stream>>>(bv, Gp, cPrev, wsi, cNext, hTn);
    logitsK<<<dim3(125, LDSP), 256, 0, stream>>>(Wo, hTn, P);
    logitsRedK<<<NVCH, 256, 0, stream>>>(P, bo, cs);
    redSelK<<<1, 1024, 0, stream>>>(ws, j);
  }
  outK<<<3, 256, 0, stream>>>(ws, (float*)d_out);
}

// Round 5
// 2292.571 us; speedup vs baseline: 1.0271x; 1.0271x over previous
//
#include <hip/hip_runtime.h>
#include <math.h>
#include <float.h>

namespace {

constexpr int Bb = 8, Kk = 4, BKn = 32, Dd = 1024, Ff = 4096, Vv = 32000, Tt = 16;
constexpr int GDS = 32, GDC = 32;        // gates d-split / d-chunk  (32*32 = 1024)
constexpr int LDSP = 8, LDC = 128;       // logits d-split / d-chunk (8*128 = 1024)
constexpr int NVCH = 500;                // logits vocab chunks of 64
constexpr int EOSt = 2, PADt = 0;
constexpr float BIGf = 1e9f, EOSSf = 1000.0f;

// ---- workspace layout (float indices) ----
constexpr size_t OFF_HTN = 0;                                   // hTn [1024][32]
constexpr size_t OFF_CB0 = OFF_HTN + (size_t)Dd * BKn;          // c ping [32][1024]
constexpr size_t OFF_CB1 = OFF_CB0 + (size_t)BKn * Dd;          // c pong
constexpr size_t OFF_GP  = OFF_CB1 + (size_t)BKn * Dd;          // gate partials [32][32][4096]
constexpr size_t OFF_PL  = OFF_GP  + (size_t)GDS * BKn * Ff;    // logit partials [8][4][32000][8]
constexpr size_t OFF_CS  = OFF_PL  + (size_t)LDSP * 4 * Vv * 8; // chunk stats [500][32][12]
constexpr size_t OFF_SC  = OFF_CS  + (size_t)NVCH * BKn * 12;   // scores [32]
constexpr size_t OFF_INT = OFF_SC  + BKn;                       // int region
constexpr int IW = 0, ISTOP = 32, IPREV = 40, IBUFA = 72, IBUFB = IBUFA + Bb * Kk * Tt;

__device__ inline void ins4(float v, int id, float tv[4], int ti[4]) {
#pragma unroll
  for (int r = 0; r < 4; r++) {
    bool better = (v > tv[r]) || (v == tv[r] && id < ti[r]);
    if (better) { float fv = tv[r]; int fi = ti[r]; tv[r] = v; ti[r] = id; v = fv; id = fi; }
  }
}

// merge per-lane sorted top-4 into group-global top-4. STARTOFF=32 -> 64-lane wave,
// STARTOFF=16 -> independent 32-lane halves.
template <int STARTOFF>
__device__ inline void merge_top4(float tv[4], int ti[4], float ov[4], int oi[4]) {
#pragma unroll
  for (int r = 0; r < 4; r++) {
    float hv = tv[0]; int hi = ti[0];
    float m = hv;
    for (int off = STARTOFF; off; off >>= 1) m = fmaxf(m, __shfl_xor(m, off));
    int c = (hv == m) ? hi : 0x7fffffff;
    for (int off = STARTOFF; off; off >>= 1) c = min(c, __shfl_xor(c, off));
    if (hv == m && hi == c) {   // this lane's head won: pop
      tv[0] = tv[1]; ti[0] = ti[1];
      tv[1] = tv[2]; ti[1] = ti[2];
      tv[2] = tv[3]; ti[2] = ti[3];
      tv[3] = -FLT_MAX; ti[3] = 0x7fffffff;
    }
    ov[r] = m; oi[r] = c;
  }
}

__global__ __launch_bounds__(256) void initK(const int* __restrict__ words,
    const float* __restrict__ h0, const float* __restrict__ c0,
    float* __restrict__ ws) {
  int* wsi = (int*)(ws + OFF_INT);
  if (blockIdx.x < 128) {
    int g = blockIdx.x * 256 + threadIdx.x;   // 0..32767
    int d = g >> 5, bk = g & 31;
    ws[OFF_HTN + g] = h0[(size_t)bk * Dd + d];   // transpose to [d][bk]
    ws[OFF_CB0 + g] = c0[g];                     // [32][1024] linear
  } else {
    int t = threadIdx.x;
    if (t < BKn) {
      ws[OFF_SC + t] = ((t & 3) == 0) ? 0.f : BIGf;
      wsi[IW + t] = words[t];
      wsi[IPREV + t] = t & 3;                    // identity gather for step 0
    }
    if (t < Bb) wsi[ISTOP + t] = 0;
    for (int i = t; i < 2 * Bb * Kk * Tt; i += 256) wsi[IBUFA + i] = 0;
  }
}

// gates partial GEMM. grid (32, 32): x = 128-col tile of f, y = d-chunk of 32.
// 256 thr = 32 col-threads (float4) x 8 beam-groups (4 beams each).
__global__ __launch_bounds__(256) void gatesK(const float* __restrict__ Wx,
    const float* __restrict__ Wh, const float* __restrict__ E,
    const float* __restrict__ hTn, const int* __restrict__ wsi,
    float* __restrict__ Gp) {
  __shared__ float xs[GDC][BKn], hs[GDC][BKn];
  int tid = threadIdx.x;
  int d0 = blockIdx.y * GDC;
  {
    int bk = tid & 31, dq = tid >> 5;           // dq 0..7, 4 d each
    int w = wsi[IW + bk];
    int src = (bk & ~3) | wsi[IPREV + bk];
    const float* Erow = E + (size_t)w * Dd + d0;
#pragma unroll
    for (int k = 0; k < 4; k++) {
      int d = dq * 4 + k;
      xs[d][bk] = Erow[d];
      hs[d][bk] = hTn[(size_t)(d0 + d) * BKn + src];
    }
  }
  __syncthreads();
  int ct = tid & 31, bg = tid >> 5;             // 32 col-threads, 8 beam-groups
  int f0 = blockIdx.x * 128 + ct * 4;
  float acc[4][4];                               // [col][beam-in-group]
#pragma unroll
  for (int c = 0; c < 4; c++)
#pragma unroll
    for (int i = 0; i < 4; i++) acc[c][i] = 0.f;
#pragma unroll 4
  for (int d = 0; d < GDC; ++d) {
    float4 wx = *(const float4*)(Wx + (size_t)(d0 + d) * Ff + f0);
    float4 wh = *(const float4*)(Wh + (size_t)(d0 + d) * Ff + f0);
    float4 x4 = *(const float4*)&xs[d][bg * 4];
    float4 h4 = *(const float4*)&hs[d][bg * 4];
    float xv[4] = {x4.x, x4.y, x4.z, x4.w};
    float hv[4] = {h4.x, h4.y, h4.z, h4.w};
    float wxc[4] = {wx.x, wx.y, wx.z, wx.w};
    float whc[4] = {wh.x, wh.y, wh.z, wh.w};
#pragma unroll
    for (int c = 0; c < 4; c++)
#pragma unroll
      for (int i = 0; i < 4; i++)
        acc[c][i] = fmaf(xv[i], wxc[c], fmaf(hv[i], whc[c], acc[c][i]));
  }
#pragma unroll
  for (int i = 0; i < 4; i++) {
    int bk = bg * 4 + i;
    float4 o = {acc[0][i], acc[1][i], acc[2][i], acc[3][i]};
    *(float4*)(Gp + ((size_t)blockIdx.y * BKn + bk) * Ff + f0) = o;
  }
}

// reduce 32 gate partials (2-way split over threads) + bias -> nonlinearity;
// gathers c by prev; writes c_new, hTn. grid (32, 8): block = (beam, 128-dc chunk).
__global__ __launch_bounds__(256) void lstmK(const float* __restrict__ bvec,
    const float* __restrict__ Gp, const float* __restrict__ cPrev,
    const int* __restrict__ wsi, float* __restrict__ cNew,
    float* __restrict__ hTn) {
  __shared__ float part[4][128];
  int bk = blockIdx.x;
  int dcl = threadIdx.x & 127;
  int half = threadIdx.x >> 7;
  int dc = blockIdx.y * 128 + dcl;
  float s[4] = {0.f, 0.f, 0.f, 0.f};
#pragma unroll 4
  for (int dsl = 0; dsl < 16; dsl++) {
    int ds = half * 16 + dsl;
    const float* row = Gp + ((size_t)ds * BKn + bk) * Ff;
#pragma unroll
    for (int g = 0; g < 4; g++) s[g] += row[(size_t)g * Dd + dc];
  }
  if (half == 1) {
#pragma unroll
    for (int g = 0; g < 4; g++) part[g][dcl] = s[g];
  }
  __syncthreads();
  if (half == 0) {
    float gi = s[0] + part[0][dcl] + bvec[dc];
    float gf = s[1] + part[1][dcl] + bvec[Dd + dc];
    float gg = s[2] + part[2][dcl] + bvec[2 * Dd + dc];
    float go = s[3] + part[3][dcl] + bvec[3 * Dd + dc];
    int src = (bk & ~3) | wsi[IPREV + bk];
    float c = cPrev[(size_t)src * Dd + dc];
    float si = 1.f / (1.f + expf(-gi));
    float sf = 1.f / (1.f + expf(-gf));
    float so = 1.f / (1.f + expf(-go));
    float tg = tanhf(gg);
    float cn = sf * c + si * tg;
    float hn = so * tanhf(cn);
    cNew[(size_t)bk * Dd + dc] = cn;
    hTn[(size_t)dc * BKn + bk] = hn;
  }
}

// logits partial GEMM. grid (125, 8): x = 256-col tile of v, y = d-chunk of 128.
// P layout: [ds][bg][32000][8 beams], stores contiguous 32B per (thread,col).
__global__ __launch_bounds__(256) void logitsK(const float* __restrict__ Wo,
    const float* __restrict__ hTn, float* __restrict__ P) {
  __shared__ float hs[LDC][BKn];
  int tid = threadIdx.x;
  int d0 = blockIdx.y * LDC;
  {
    int bk = tid & 31, dq = tid >> 5;
#pragma unroll
    for (int k = 0; k < 16; k++) {
      int d = dq * 16 + k;
      hs[d][bk] = hTn[(size_t)(d0 + d) * BKn + bk];
    }
  }
  __syncthreads();
  int ct = tid & 63, bg = tid >> 6;
  size_t v0 = (size_t)blockIdx.x * 256 + ct * 4;
  float acc[4][8];
#pragma unroll
  for (int c = 0; c < 4; c++)
#pragma unroll
    for (int i = 0; i < 8; i++) acc[c][i] = 0.f;
#pragma unroll 8
  for (int d = 0; d < LDC; ++d) {
    float4 w = *(const float4*)(Wo + (size_t)(d0 + d) * Vv + v0);
    float4 hlo = *(const float4*)&hs[d][bg * 8];
    float4 hhi = *(const float4*)&hs[d][bg * 8 + 4];
    float hv[8] = {hlo.x, hlo.y, hlo.z, hlo.w, hhi.x, hhi.y, hhi.z, hhi.w};
    float wc[4] = {w.x, w.y, w.z, w.w};
#pragma unroll
    for (int c = 0; c < 4; c++)
#pragma unroll
      for (int i = 0; i < 8; i++)
        acc[c][i] = fmaf(hv[i], wc[c], acc[c][i]);
  }
  float* base = P + ((size_t)(blockIdx.y * 4 + bg) * Vv) * 8;
#pragma unroll
  for (int c = 0; c < 4; c++) {
    float4 lo = {acc[c][0], acc[c][1], acc[c][2], acc[c][3]};
    float4 hi = {acc[c][4], acc[c][5], acc[c][6], acc[c][7]};
    *(float4*)(base + (v0 + c) * 8) = lo;
    *(float4*)(base + (v0 + c) * 8 + 4) = hi;
  }
}

// reduce 8 logit partials + bias -> full logits in LDS -> chunk stats (max/sumexp/top4).
// grid 500 blocks x 256 threads; block = 64 vocab cols; 4 waves x 8 beams for stats.
__global__ __launch_bounds__(256) void logitsRedK(const float* __restrict__ P,
    const float* __restrict__ bo, float* __restrict__ cs) {
  __shared__ float sd[BKn][64];
  int tid = threadIdx.x;
  int vl = tid & 63, bh = tid >> 6;      // bh: beam group 0..3 (8 beams each)
  size_t v = (size_t)blockIdx.x * 64 + vl;
  float b = bo[v];
  {
    float4 lo = {0, 0, 0, 0}, hi = {0, 0, 0, 0};
#pragma unroll
    for (int ds = 0; ds < LDSP; ds++) {
      const float* p = P + ((size_t)(ds * 4 + bh) * Vv + v) * 8;
      float4 a = *(const float4*)p;
      float4 c = *(const float4*)(p + 4);
      lo.x += a.x; lo.y += a.y; lo.z += a.z; lo.w += a.w;
      hi.x += c.x; hi.y += c.y; hi.z += c.z; hi.w += c.w;
    }
    int bk0 = bh * 8;
    sd[bk0 + 0][vl] = lo.x + b; sd[bk0 + 1][vl] = lo.y + b;
    sd[bk0 + 2][vl] = lo.z + b; sd[bk0 + 3][vl] = lo.w + b;
    sd[bk0 + 4][vl] = hi.x + b; sd[bk0 + 5][vl] = hi.y + b;
    sd[bk0 + 6][vl] = hi.z + b; sd[bk0 + 7][vl] = hi.w + b;
  }
  __syncthreads();
  int lane = tid & 63;
  int wv_ = tid >> 6;                     // 4 waves x 8 beams = 32 beams
  int i0 = blockIdx.x * 64 + lane;
  for (int bb = 0; bb < 8; ++bb) {
    int bk = wv_ * 8 + bb;
    float v0f = sd[bk][lane];
    float m = v0f;
    for (int off = 32; off; off >>= 1) m = fmaxf(m, __shfl_xor(m, off));
    float se = expf(v0f - m);
    for (int off = 32; off; off >>= 1) se += __shfl_xor(se, off);
    float tv[4]; int ti[4];
#pragma unroll
    for (int r = 0; r < 4; r++) { tv[r] = -FLT_MAX; ti[r] = 0x7fffffff; }
    ins4(v0f, i0, tv, ti);
    float ov[4]; int oi[4];
    merge_top4<32>(tv, ti, ov, oi);
    if (lane == 0) {
      float* p = cs + ((size_t)blockIdx.x * BKn + bk) * 12;
      p[0] = m; p[1] = se;
#pragma unroll
      for (int r = 0; r < 4; r++) { p[2 + r] = ov[r]; p[6 + r] = __int_as_float(oi[r]); }
    }
  }
}

// fused: per-beam merge of 500 chunk stats -> lse + top4; then exact selection,
// EOS logic, buf ping-pong. One block of 1024 threads. No runtime-indexed arrays.
__global__ __launch_bounds__(1024) void redSelK(float* __restrict__ ws, int step) {
  __shared__ float bt_s[BKn][8];
  __shared__ int s_tok[BKn], s_prevb[BKn];
  int* wsi = (int*)(ws + OFF_INT);
  const float* cs = ws + OFF_CS;
  int tid = threadIdx.x;
  int wv = tid >> 6, lane = tid & 63;
  {
    int half = lane >> 5, l32 = lane & 31;
    int bk = wv * 2 + half;                 // 16 waves x 2 halves = 32 beams
    float tv[4]; int ti[4];
#pragma unroll
    for (int r = 0; r < 4; r++) { tv[r] = -FLT_MAX; ti[r] = 0x7fffffff; }
    float cm[16], csum[16]; bool val[16];
    float lm = -FLT_MAX;
#pragma unroll
    for (int q = 0; q < 16; q++) {
      int c = l32 + 32 * q;
      val[q] = c < NVCH;
      if (val[q]) {
        const float* p = cs + ((size_t)c * BKn + bk) * 12;
        cm[q] = p[0]; csum[q] = p[1];
        lm = fmaxf(lm, cm[q]);
#pragma unroll
        for (int r = 0; r < 4; r++) ins4(p[2 + r], __float_as_int(p[6 + r]), tv, ti);
      } else { cm[q] = -FLT_MAX; csum[q] = 0.f; }
    }
    float M = lm;
    for (int off = 16; off; off >>= 1) M = fmaxf(M, __shfl_xor(M, off));
    float ls = 0.f;
#pragma unroll
    for (int q = 0; q < 16; q++) if (val[q]) ls += csum[q] * expf(cm[q] - M);
    for (int off = 16; off; off >>= 1) ls += __shfl_xor(ls, off);
    float lse = M + logf(ls);
    float ov[4]; int oi[4];
    merge_top4<16>(tv, ti, ov, oi);
    if (l32 == 0) {
#pragma unroll
      for (int r = 0; r < 4; r++) {
        bt_s[bk][r] = lse - ov[r];
        bt_s[bk][4 + r] = __int_as_float(oi[r]);
      }
    }
  }
  __syncthreads();
  if (tid < Bb) {
    int b = tid;
    int st = wsi[ISTOP + b];
    float sc[4];
#pragma unroll
    for (int k = 0; k < 4; k++) sc[k] = ws[OFF_SC + b * 4 + k];
    float cval[16]; int ctok[16];
#pragma unroll
    for (int kb = 0; kb < 4; kb++)
#pragma unroll
      for (int r = 0; r < 4; r++) {
        cval[kb * 4 + r] = bt_s[b * 4 + kb][r] + sc[kb];
        ctok[kb * 4 + r] = __float_as_int(bt_s[b * 4 + kb][4 + r]);
      }
    float selS[4]; int selW[4], prevK[4];
    int usedMask = 0;
#pragma unroll
    for (int r = 0; r < 4; r++) {
      int best = -1; float bv = FLT_MAX;
#pragma unroll
      for (int t = 0; t < 16; t++) {
        if (!((usedMask >> t) & 1) && cval[t] < bv) { bv = cval[t]; best = t; }
      }
      usedMask |= 1 << best;
      int tok = 0;
#pragma unroll
      for (int t = 0; t < 16; t++) if (t == best) tok = ctok[t];   // no runtime index
      selS[r] = bv; selW[r] = tok; prevK[r] = best >> 2;
    }
    bool eos[4];
#pragma unroll
    for (int r = 0; r < 4; r++) eos[r] = (selW[r] == EOSt);
    bool first = eos[0] && !st;
#pragma unroll
    for (int r = 0; r < 4; r++) if (eos[r] && !first && !st) selS[r] = EOSSf;
#pragma unroll
    for (int k = 0; k < 4; k++) {
      int tok = st ? PADt : (first ? EOSt : selW[k]);
      int pb  = st ? k : prevK[k];
      s_tok[b * 4 + k] = tok;
      s_prevb[b * 4 + k] = pb;
      if (!st) { ws[OFF_SC + b * 4 + k] = selS[k]; wsi[IW + b * 4 + k] = selW[k]; }
      wsi[IPREV + b * 4 + k] = prevK[k];
    }
    wsi[ISTOP + b] = (st || first) ? 1 : 0;
  }
  __syncthreads();
  if (tid < 512) {
    const int* br = wsi + (((step & 1) == 0) ? IBUFA : IBUFB);
    int* bw = wsi + (((step & 1) == 0) ? IBUFB : IBUFA);
    int bkk = tid >> 4, t = tid & 15;
    int pb = s_prevb[bkk];
    int src = ((bkk & ~3) | pb) * Tt + t;
    int val = br[src];
    if (t == step) val = s_tok[bkk];
    bw[tid] = val;
  }
}

// Output read as float32 by harness: tokens as float values, scores as floats.
__global__ __launch_bounds__(256) void outK(const float* __restrict__ ws,
                                            float* __restrict__ out) {
  const int* wsi = (const int*)(ws + OFF_INT);
  int g = blockIdx.x * 256 + threadIdx.x;
  if (g < Bb * Kk * Tt) {
    out[g] = (float)wsi[IBUFA + g];               // final buf in A after 16 steps
  } else if (g < Bb * Kk * Tt + BKn) {
    out[g] = ws[OFF_SC + (g - Bb * Kk * Tt)];
  }
}

} // namespace

extern "C" void kernel_launch(void* const* d_in, const int* in_sizes, int n_in,
                              void* d_out, int out_size, void* d_ws, size_t ws_size,
                              hipStream_t stream) {
  (void)in_sizes; (void)n_in; (void)out_size; (void)ws_size;
  const int*   words = (const int*)d_in[0];
  const float* h0 = (const float*)d_in[1];
  const float* c0 = (const float*)d_in[2];
  const float* E  = (const float*)d_in[3];
  const float* Wx = (const float*)d_in[4];
  const float* Wh = (const float*)d_in[5];
  const float* bv = (const float*)d_in[6];
  const float* Wo = (const float*)d_in[7];
  const float* bo = (const float*)d_in[8];
  float* ws = (float*)d_ws;
  float* hTn = ws + OFF_HTN;
  float* cb0 = ws + OFF_CB0;
  float* cb1 = ws + OFF_CB1;
  float* Gp  = ws + OFF_GP;
  float* P   = ws + OFF_PL;
  float* cs  = ws + OFF_CS;
  int*   wsi = (int*)(ws + OFF_INT);

  initK<<<129, 256, 0, stream>>>(words, h0, c0, ws);
  for (int j = 0; j < Tt; j++) {
    float* cPrev = (j & 1) ? cb1 : cb0;
    float* cNext = (j & 1) ? cb0 : cb1;
    gatesK<<<dim3(32, GDS), 256, 0, stream>>>(Wx, Wh, E, hTn, wsi, Gp);
    lstmK<<<dim3(32, 8), 256, 0, stream>>>(bv, Gp, cPrev, wsi, cNext, hTn);
    logitsK<<<dim3(125, LDSP), 256, 0, stream>>>(Wo, hTn, P);
    logitsRedK<<<NVCH, 256, 0, stream>>>(P, bo, cs);
    redSelK<<<1, 1024, 0, stream>>>(ws, j);
  }
  outK<<<3, 256, 0, stream>>>(ws, (float*)d_out);
}